// Round 11
// baseline (601.990 us; speedup 1.0000x reference)
//
#include <hip/hip_runtime.h>
#include <math.h>

#define BB 4
#define NN 2048
#define KK 20
#define INFPK 0xFFFFFFFFFFFFFFFFull

static __device__ __forceinline__ float lrelu(float z) {
    return z >= 0.f ? z : 0.2f * z;
}

// 64-bit full-wave min via paired 32-bit DPP (row_shr 1,2,4,8 + row_bcast 15,31),
// broadcast via readlane 63. Validated on this HW in R7-R10 (passed).
template<int CTRL>
static __device__ __forceinline__ unsigned long long dpp_min64_step(unsigned long long v) {
    unsigned lo = (unsigned)__builtin_amdgcn_update_dpp(
        (int)0xFFFFFFFFu, (int)(unsigned)v, CTRL, 0xF, 0xF, false);
    unsigned hi = (unsigned)__builtin_amdgcn_update_dpp(
        (int)0xFFFFFFFFu, (int)(unsigned)(v >> 32), CTRL, 0xF, 0xF, false);
    unsigned long long t = ((unsigned long long)hi << 32) | lo;
    return t < v ? t : v;
}
static __device__ __forceinline__ unsigned long long wave_min64_bcast(unsigned long long v) {
    v = dpp_min64_step<0x111>(v);
    v = dpp_min64_step<0x112>(v);
    v = dpp_min64_step<0x114>(v);
    v = dpp_min64_step<0x118>(v);
    v = dpp_min64_step<0x142>(v);
    v = dpp_min64_step<0x143>(v);
    unsigned lo = (unsigned)__builtin_amdgcn_readlane((int)(unsigned)v, 63);
    unsigned hi = (unsigned)__builtin_amdgcn_readlane((int)(unsigned)(v >> 32), 63);
    return ((unsigned long long)hi << 32) | lo;
}

// ---------------- sq: per-point squared norm (identical chain to R2-R9) -----
template<int C>
__global__ __launch_bounds__(256) void sq_kernel(const float* __restrict__ x,
                                                 float* __restrict__ sq) {
    int i = blockIdx.x * 256 + threadIdx.x;
    if (i >= BB * NN) return;
    int b = i / NN, n = i - b * NN;
    const float* xb = x + (size_t)b * C * NN + n;
    float s = 0.f;
    #pragma unroll
    for (int c = 0; c < C; ++c) {
        float v = xb[(size_t)c * NN];
        s = fmaf(v, v, s);
    }
    sq[i] = s;
}

// ---------------- dist: keys[b][i][j] = monokey(sq_i + sq_j - 2*x_i.x_j) ----
// Register-tiled symmetric GEMM (final_kernel structure: 64x64 tile, 4x4 per
// thread, 32 KB LDS -> 4 blocks/CU). acc per (i,j) is ONE ascending-c fmaf
// chain from 0 (k-tiles ascending, inner c ascending) == the chain every
// passing round used; d-expression and key transform bit-identical.
template<int C>
__global__ __launch_bounds__(256, 4) void dist_kernel(const float* __restrict__ x,
                                                      const float* __restrict__ sq,
                                                      unsigned* __restrict__ keys) {
    __shared__ float xi[64][64];   // [c][i]
    __shared__ float xj[64][64];   // [c][j]
    int blk = blockIdx.x;
    int jt = blk & 31;
    int it = (blk >> 5) & 31;
    int b  = blk >> 10;
    int t = threadIdx.x;
    int tn = t & 15, to = t >> 4;   // j-group, i-group

    float acc[4][4];   // [i][j]
    #pragma unroll
    for (int i = 0; i < 4; ++i)
        #pragma unroll
        for (int j = 0; j < 4; ++j) acc[i][j] = 0.f;

    const float* xb = x + (size_t)b * C * NN;
    for (int c0 = 0; c0 < C; c0 += 64) {
        const int CT = (C - c0) < 64 ? (C - c0) : 64;
        __syncthreads();
        for (int e = t * 4; e < CT * 64; e += 1024) {
            int c = e >> 6, i = e & 63;
            *(float4*)&xi[c][i] = *(const float4*)&xb[(size_t)(c0 + c) * NN + it * 64 + i];
        }
        for (int e = t * 4; e < CT * 64; e += 1024) {
            int c = e >> 6, j = e & 63;
            *(float4*)&xj[c][j] = *(const float4*)&xb[(size_t)(c0 + c) * NN + jt * 64 + j];
        }
        __syncthreads();
        for (int c = 0; c < CT; ++c) {
            float4 iv = *(float4*)&xi[c][to * 4];
            float4 jv = *(float4*)&xj[c][tn * 4];
            acc[0][0] = fmaf(iv.x, jv.x, acc[0][0]);
            acc[0][1] = fmaf(iv.x, jv.y, acc[0][1]);
            acc[0][2] = fmaf(iv.x, jv.z, acc[0][2]);
            acc[0][3] = fmaf(iv.x, jv.w, acc[0][3]);
            acc[1][0] = fmaf(iv.y, jv.x, acc[1][0]);
            acc[1][1] = fmaf(iv.y, jv.y, acc[1][1]);
            acc[1][2] = fmaf(iv.y, jv.z, acc[1][2]);
            acc[1][3] = fmaf(iv.y, jv.w, acc[1][3]);
            acc[2][0] = fmaf(iv.z, jv.x, acc[2][0]);
            acc[2][1] = fmaf(iv.z, jv.y, acc[2][1]);
            acc[2][2] = fmaf(iv.z, jv.z, acc[2][2]);
            acc[2][3] = fmaf(iv.z, jv.w, acc[2][3]);
            acc[3][0] = fmaf(iv.w, jv.x, acc[3][0]);
            acc[3][1] = fmaf(iv.w, jv.y, acc[3][1]);
            acc[3][2] = fmaf(iv.w, jv.z, acc[3][2]);
            acc[3][3] = fmaf(iv.w, jv.w, acc[3][3]);
        }
    }

    const float* sqb = sq + b * NN;
    float4 sqjv = *(const float4*)&sqb[jt * 64 + tn * 4];
    float sqju[4] = {sqjv.x, sqjv.y, sqjv.z, sqjv.w};
    #pragma unroll
    for (int i = 0; i < 4; ++i) {
        float sqi = sqb[it * 64 + to * 4 + i];
        uint4 kv;
        unsigned ks[4];
        #pragma unroll
        for (int u = 0; u < 4; ++u) {
            float d = sqi + sqju[u] - 2.f * acc[i][u];
            unsigned v = __float_as_uint(d);
            ks[u] = v ^ ((unsigned)((int)v >> 31) | 0x80000000u);
        }
        kv.x = ks[0]; kv.y = ks[1]; kv.z = ks[2]; kv.w = ks[3];
        *(uint4*)&keys[((size_t)b * NN + it * 64 + to * 4 + i) * NN + jt * 64 + tn * 4] = kv;
    }
}

// ---------------- select: top-20 per query from global keys ----------------
// One wave per query, 4 waves/block, NO LDS, NO barriers -> 8+ waves/SIMD so
// the DPP chains are hidden by independent waves (the fused kernel's barrier-
// locked phases prevented this). Queue machinery proven in R8/R9/R10.
// u64 min on distinct pk=(key<<12)|j == exact (d, j) lex — matches lax.top_k.
__global__ __launch_bounds__(256) void select_kernel(const unsigned* __restrict__ keys,
                                                     int* __restrict__ idx) {
    int t = threadIdx.x;
    int lane = t & 63, wid = t >> 6;
    int Q = blockIdx.x * 4 + wid;            // global query in [0, BB*NN)
    const unsigned* row = keys + (size_t)Q * NN;

    unsigned long long h0 = INFPK, h1 = INFPK, h2 = INFPK, h3 = INFPK;

#define PK_INS(KEY, J) {                                                      \
        unsigned long long v =                                                \
            ((unsigned long long)(KEY) << 12) | (unsigned)(J);                \
        if (v < h3) {                                                         \
            unsigned long long nh3 = h2 > v ? h2 : v;                         \
            unsigned long long t2  = h2 < v ? h2 : v;                         \
            unsigned long long nh2 = h1 > t2 ? h1 : t2;                       \
            unsigned long long t1  = h1 < v ? h1 : v;                         \
            unsigned long long nh1 = h0 > t1 ? h0 : t1;                       \
            unsigned long long nh0 = h0 < v ? h0 : v;                         \
            h0 = nh0; h1 = nh1; h2 = nh2; h3 = nh3;                           \
        } }
#define PK_INS_THR(KEY, J) {                                                  \
        unsigned long long v =                                                \
            ((unsigned long long)(KEY) << 12) | (unsigned)(J);                \
        if (v > thr && v < h3) {                                              \
            unsigned long long nh3 = h2 > v ? h2 : v;                         \
            unsigned long long t2  = h2 < v ? h2 : v;                         \
            unsigned long long nh2 = h1 > t2 ? h1 : t2;                       \
            unsigned long long t1  = h1 < v ? h1 : v;                         \
            unsigned long long nh1 = h0 > t1 ? h0 : t1;                       \
            unsigned long long nh0 = h0 < v ? h0 : v;                         \
            h0 = nh0; h1 = nh1; h2 = nh2; h3 = nh3;                           \
        } }
    // lane reads uint4 s at element 4*(lane + 64*s): j = 4*lane + 256*s + u
#define ROW_RD(s) uint4 V##s = *(const uint4*)(row + 4 * (lane + 64 * (s)));
#define ROW_INS(s)     { PK_INS(V##s.x, 4*lane + 256*(s) + 0)                 \
                         PK_INS(V##s.y, 4*lane + 256*(s) + 1)                 \
                         PK_INS(V##s.z, 4*lane + 256*(s) + 2)                 \
                         PK_INS(V##s.w, 4*lane + 256*(s) + 3) }
#define ROW_INS_THR(s) { PK_INS_THR(V##s.x, 4*lane + 256*(s) + 0)             \
                         PK_INS_THR(V##s.y, 4*lane + 256*(s) + 1)             \
                         PK_INS_THR(V##s.z, 4*lane + 256*(s) + 2)             \
                         PK_INS_THR(V##s.w, 4*lane + 256*(s) + 3) }

    {   // build
        ROW_RD(0) ROW_RD(1) ROW_RD(2) ROW_RD(3)
        ROW_RD(4) ROW_RD(5) ROW_RD(6) ROW_RD(7)
        ROW_INS(0) ROW_INS(1) ROW_INS(2) ROW_INS(3)
        ROW_INS(4) ROW_INS(5) ROW_INS(6) ROW_INS(7)
    }

    int* orow = idx + (size_t)Q * KK;
    unsigned long long thr = 0;
    int popped = 0;
    #pragma unroll 1
    for (int rr = 0; rr < KK; ++rr) {
        unsigned long long g = wave_min64_bcast(h0);
        if (lane == 0) orow[rr] = (int)(g & 0xFFFu);
        if (h0 == g) {
            thr = g;
            ++popped;
            h0 = h1; h1 = h2; h2 = h3; h3 = INFPK;
            if (h0 == INFPK && popped < 32) {   // rare refill
                ROW_RD(0) ROW_RD(1) ROW_RD(2) ROW_RD(3)
                ROW_RD(4) ROW_RD(5) ROW_RD(6) ROW_RD(7)
                ROW_INS_THR(0) ROW_INS_THR(1) ROW_INS_THR(2) ROW_INS_THR(3)
                ROW_INS_THR(4) ROW_INS_THR(5) ROW_INS_THR(6) ROW_INS_THR(7)
            }
        }
    }
#undef PK_INS
#undef PK_INS_THR
#undef ROW_RD
#undef ROW_INS
#undef ROW_INS_THR
}

// ---------------- fallback fused knn (R10, proven @514us total) -------------
template<int C>
__global__ __launch_bounds__(512) void knn_kernel(const float* __restrict__ x,
                                                  int* __restrict__ idx) {
    const int QT = 8;
    __shared__ unsigned dl[QT][NN];
    __shared__ float xq[QT][C];
    __shared__ float sqq[QT];
    int blk = blockIdx.x;
    int b = blk / (NN / QT);
    int q0 = (blk - b * (NN / QT)) * QT;
    int t = threadIdx.x;
    int lane = t & 63, wid = t >> 6;

    const float* xb = x + (size_t)b * C * NN;
    for (int e = t; e < QT * C; e += 512) {
        int q = e / C, c = e - q * C;
        xq[q][c] = xb[(size_t)c * NN + q0 + q];
    }
    __syncthreads();
    if (t < QT) {
        float s = 0.f;
        #pragma unroll 4
        for (int c = 0; c < C; ++c) s = fmaf(xq[t][c], xq[t][c], s);
        sqq[t] = s;
    }
    __syncthreads();

    float acc[QT][4];
    #pragma unroll
    for (int q = 0; q < QT; ++q)
        #pragma unroll
        for (int u = 0; u < 4; ++u) acc[q][u] = 0.f;
    float sqa0 = 0.f, sqa1 = 0.f, sqa2 = 0.f, sqa3 = 0.f;

    for (int c = 0; c < C; ++c) {
        float4 xjv = *(const float4*)&xb[(size_t)c * NN + 4 * t];
        #pragma unroll
        for (int q = 0; q < QT; ++q) {
            float xqc = xq[q][c];
            acc[q][0] = fmaf(xqc, xjv.x, acc[q][0]);
            acc[q][1] = fmaf(xqc, xjv.y, acc[q][1]);
            acc[q][2] = fmaf(xqc, xjv.z, acc[q][2]);
            acc[q][3] = fmaf(xqc, xjv.w, acc[q][3]);
        }
        sqa0 = fmaf(xjv.x, xjv.x, sqa0);
        sqa1 = fmaf(xjv.y, xjv.y, sqa1);
        sqa2 = fmaf(xjv.z, xjv.z, sqa2);
        sqa3 = fmaf(xjv.w, xjv.w, sqa3);
    }
    float sqju[4] = {sqa0, sqa1, sqa2, sqa3};

    int wbase = ((t >> 3) << 5) | (((t ^ (t >> 3)) & 7) << 2);
    #pragma unroll
    for (int q = 0; q < QT; ++q) {
        float sqi = sqq[q];
        uint4 kv;
        unsigned ks[4];
        #pragma unroll
        for (int u = 0; u < 4; ++u) {
            float d = sqi + sqju[u] - 2.f * acc[q][u];
            unsigned v = __float_as_uint(d);
            ks[u] = v ^ ((unsigned)((int)v >> 31) | 0x80000000u);
        }
        kv.x = ks[0]; kv.y = ks[1]; kv.z = ks[2]; kv.w = ks[3];
        *(uint4*)&dl[q][wbase] = kv;
    }
    __syncthreads();

    unsigned* dq = &dl[wid][0];
    int r7 = lane & 7;
    int lanebase = lane << 5;
    unsigned long long h0 = INFPK, h1 = INFPK, h2 = INFPK, h3 = INFPK;

#define PK_INS(KEY, LO) {                                                     \
        unsigned long long v =                                                \
            ((unsigned long long)(KEY) << 12) | (unsigned)(lanebase + (LO));  \
        if (v < h3) {                                                         \
            unsigned long long nh3 = h2 > v ? h2 : v;                         \
            unsigned long long t2  = h2 < v ? h2 : v;                         \
            unsigned long long nh2 = h1 > t2 ? h1 : t2;                       \
            unsigned long long t1  = h1 < v ? h1 : v;                         \
            unsigned long long nh1 = h0 > t1 ? h0 : t1;                       \
            unsigned long long nh0 = h0 < v ? h0 : v;                         \
            h0 = nh0; h1 = nh1; h2 = nh2; h3 = nh3;                           \
        } }
#define PK_INS_THR(KEY, LO) {                                                 \
        unsigned long long v =                                                \
            ((unsigned long long)(KEY) << 12) | (unsigned)(lanebase + (LO));  \
        if (v > thr && v < h3) {                                              \
            unsigned long long nh3 = h2 > v ? h2 : v;                         \
            unsigned long long t2  = h2 < v ? h2 : v;                         \
            unsigned long long nh2 = h1 > t2 ? h1 : t2;                       \
            unsigned long long t1  = h1 < v ? h1 : v;                         \
            unsigned long long nh1 = h0 > t1 ? h0 : t1;                       \
            unsigned long long nh0 = h0 < v ? h0 : v;                         \
            h0 = nh0; h1 = nh1; h2 = nh2; h3 = nh3;                           \
        } }
#define CHUNK_RD(c) uint4 V##c = *(const uint4*)(dq + lanebase + (((c) ^ r7) << 2));
#define CHUNK_INS(c)     { PK_INS(V##c.x, 4*(c)+0) PK_INS(V##c.y, 4*(c)+1)        \
                           PK_INS(V##c.z, 4*(c)+2) PK_INS(V##c.w, 4*(c)+3) }
#define CHUNK_INS_THR(c) { PK_INS_THR(V##c.x, 4*(c)+0) PK_INS_THR(V##c.y, 4*(c)+1) \
                           PK_INS_THR(V##c.z, 4*(c)+2) PK_INS_THR(V##c.w, 4*(c)+3) }

    {
        CHUNK_RD(0) CHUNK_RD(1) CHUNK_RD(2) CHUNK_RD(3)
        CHUNK_RD(4) CHUNK_RD(5) CHUNK_RD(6) CHUNK_RD(7)
        CHUNK_INS(0) CHUNK_INS(1) CHUNK_INS(2) CHUNK_INS(3)
        CHUNK_INS(4) CHUNK_INS(5) CHUNK_INS(6) CHUNK_INS(7)
    }

    int* orow = idx + (size_t)(b * NN + q0 + wid) * KK;
    unsigned long long thr = 0;
    int popped = 0;
    #pragma unroll 1
    for (int rr = 0; rr < KK; ++rr) {
        unsigned long long g = wave_min64_bcast(h0);
        if (lane == 0) orow[rr] = (int)(g & 0xFFFu);
        if (h0 == g) {
            thr = g;
            ++popped;
            h0 = h1; h1 = h2; h2 = h3; h3 = INFPK;
            if (h0 == INFPK && popped < 32) {
                CHUNK_RD(0) CHUNK_RD(1) CHUNK_RD(2) CHUNK_RD(3)
                CHUNK_RD(4) CHUNK_RD(5) CHUNK_RD(6) CHUNK_RD(7)
                CHUNK_INS_THR(0) CHUNK_INS_THR(1) CHUNK_INS_THR(2) CHUNK_INS_THR(3)
                CHUNK_INS_THR(4) CHUNK_INS_THR(5) CHUNK_INS_THR(6) CHUNK_INS_THR(7)
            }
        }
    }
#undef PK_INS
#undef PK_INS_THR
#undef CHUNK_RD
#undef CHUNK_INS
#undef CHUNK_INS_THR
}

// ---------------- p/t: p = Wn·x, t = (Wc-Wn)·x ----------------
template<int C, int OT>
__global__ __launch_bounds__(256) void pt_kernel(const float* __restrict__ x,
                                                 const float* __restrict__ W,
                                                 float* __restrict__ p,
                                                 float* __restrict__ tt,
                                                 int O) {
    const int NB = NN / 256;
    int blk = blockIdx.x;
    int nb = blk % NB;
    int rest = blk / NB;
    int nob = O / OT;
    int ob = rest % nob;
    int b = rest / nob;
    int t = threadIdx.x;
    int n = nb * 256 + t;
    __shared__ float wn[OT][C], wd[OT][C];
    for (int e = t; e < OT * C; e += 256) {
        int o = e / C, c = e - o * C;
        float a = W[(size_t)(ob * OT + o) * (2 * C) + c];
        float b2 = W[(size_t)(ob * OT + o) * (2 * C) + C + c];
        wn[o][c] = a;
        wd[o][c] = b2 - a;
    }
    __syncthreads();
    float ap[OT], at[OT];
    #pragma unroll
    for (int o = 0; o < OT; ++o) { ap[o] = 0.f; at[o] = 0.f; }
    const float* xb = x + (size_t)b * C * NN + n;
    for (int c = 0; c < C; ++c) {
        float xv = xb[(size_t)c * NN];
        #pragma unroll
        for (int o = 0; o < OT; ++o) {
            ap[o] = fmaf(wn[o][c], xv, ap[o]);
            at[o] = fmaf(wd[o][c], xv, at[o]);
        }
    }
    size_t base = ((size_t)b * O + ob * OT) * NN + n;
    #pragma unroll
    for (int o = 0; o < OT; ++o) {
        p[base + (size_t)o * NN] = ap[o];
        tt[base + (size_t)o * NN] = at[o];
    }
}

// ---------------- edge max ----------------
__global__ __launch_bounds__(256) void edge_kernel(const float* __restrict__ p,
                                                   const float* __restrict__ tt,
                                                   const int* __restrict__ idx,
                                                   const float* __restrict__ g,
                                                   const float* __restrict__ be,
                                                   float* __restrict__ out, int O) {
    int b = blockIdx.x / O, o = blockIdx.x - b * O;
    __shared__ float pl[NN];
    const float* pr = p + ((size_t)b * O + o) * NN;
    for (int e = threadIdx.x * 4; e < NN; e += 1024)
        *(float4*)&pl[e] = *(const float4*)&pr[e];
    __syncthreads();
    float scale = g[o] / sqrtf(1.f + 1e-5f);
    float beta = be[o];
    const float* tr = tt + ((size_t)b * O + o) * NN;
    float* orow = out + ((size_t)b * O + o) * NN;
    for (int i = threadIdx.x; i < NN; i += 256) {
        float ti = tr[i];
        const int4* ir4 = (const int4*)(idx + (size_t)(b * NN + i) * KK);
        int4 w0 = ir4[0], w1 = ir4[1], w2 = ir4[2], w3 = ir4[3], w4 = ir4[4];
        float m = -__builtin_inff();
        int js[20] = {w0.x, w0.y, w0.z, w0.w, w1.x, w1.y, w1.z, w1.w,
                      w2.x, w2.y, w2.z, w2.w, w3.x, w3.y, w3.z, w3.w,
                      w4.x, w4.y, w4.z, w4.w};
        #pragma unroll
        for (int k = 0; k < KK; ++k) {
            float y = pl[js[k]] + ti;
            m = fmaxf(m, lrelu(fmaf(scale, y, beta)));
        }
        orow[i] = m;
    }
}

// ---------------- transpose W5 ----------------
__global__ __launch_bounds__(256) void transpose_kernel(const float* __restrict__ W,
                                                        float* __restrict__ WT) {
    __shared__ float tile[32][33];
    int c0 = blockIdx.x * 32, o0 = blockIdx.y * 32;
    int tx = threadIdx.x, ty = threadIdx.y;
    #pragma unroll
    for (int i = 0; i < 32; i += 8)
        tile[ty + i][tx] = W[(size_t)(o0 + ty + i) * 256 + c0 + tx];
    __syncthreads();
    #pragma unroll
    for (int i = 0; i < 32; i += 8)
        WT[(size_t)(c0 + ty + i) * 1024 + o0 + tx] = tile[tx][ty + i];
}

// ---------------- final GEMM + fused lrelu + max ----------------
__global__ __launch_bounds__(256) void final_kernel(const float* __restrict__ x4,
                                                    const float* __restrict__ W5T,
                                                    const float* __restrict__ g,
                                                    const float* __restrict__ be,
                                                    float* __restrict__ partial) {
    const int CC = 256;
    __shared__ float xs[64][64];
    __shared__ float ws[64][64];
    int blk = blockIdx.x;
    int nb = blk & 31;
    int ob = (blk >> 5) & 15;
    int b  = blk >> 9;
    int t = threadIdx.x;
    int tn = t & 15, to = t >> 4;

    float acc[4][4];
    #pragma unroll
    for (int i = 0; i < 4; ++i)
        #pragma unroll
        for (int j = 0; j < 4; ++j) acc[i][j] = 0.f;

    for (int c0 = 0; c0 < CC; c0 += 64) {
        __syncthreads();
        #pragma unroll
        for (int e = t * 4; e < 64 * 64; e += 1024) {
            int c = e >> 6, n = e & 63;
            *(float4*)&xs[c][n] =
                *(const float4*)&x4[((size_t)b * CC + c0 + c) * NN + nb * 64 + n];
        }
        #pragma unroll
        for (int e = t * 4; e < 64 * 64; e += 1024) {
            int c = e >> 6, o = e & 63;
            *(float4*)&ws[c][o] =
                *(const float4*)&W5T[(size_t)(c0 + c) * 1024 + ob * 64 + o];
        }
        __syncthreads();
        for (int c = 0; c < 64; ++c) {
            float4 xv = *(float4*)&xs[c][tn * 4];
            float4 wv = *(float4*)&ws[c][to * 4];
            acc[0][0] = fmaf(wv.x, xv.x, acc[0][0]);
            acc[0][1] = fmaf(wv.x, xv.y, acc[0][1]);
            acc[0][2] = fmaf(wv.x, xv.z, acc[0][2]);
            acc[0][3] = fmaf(wv.x, xv.w, acc[0][3]);
            acc[1][0] = fmaf(wv.y, xv.x, acc[1][0]);
            acc[1][1] = fmaf(wv.y, xv.y, acc[1][1]);
            acc[1][2] = fmaf(wv.y, xv.z, acc[1][2]);
            acc[1][3] = fmaf(wv.y, xv.w, acc[1][3]);
            acc[2][0] = fmaf(wv.z, xv.x, acc[2][0]);
            acc[2][1] = fmaf(wv.z, xv.y, acc[2][1]);
            acc[2][2] = fmaf(wv.z, xv.z, acc[2][2]);
            acc[2][3] = fmaf(wv.z, xv.w, acc[2][3]);
            acc[3][0] = fmaf(wv.w, xv.x, acc[3][0]);
            acc[3][1] = fmaf(wv.w, xv.y, acc[3][1]);
            acc[3][2] = fmaf(wv.w, xv.z, acc[3][2]);
            acc[3][3] = fmaf(wv.w, xv.w, acc[3][3]);
        }
    }

    float rs = 1.f / sqrtf(1.f + 1e-5f);
    #pragma unroll
    for (int i = 0; i < 4; ++i) {
        int o = ob * 64 + to * 4 + i;
        float scale = g[o] * rs, beta = be[o];
        float m = -__builtin_inff();
        #pragma unroll
        for (int j = 0; j < 4; ++j)
            m = fmaxf(m, lrelu(fmaf(scale, acc[i][j], beta)));
        #pragma unroll
        for (int off = 8; off >= 1; off >>= 1)
            m = fmaxf(m, __shfl_xor(m, off));
        if (tn == 0)
            partial[(size_t)(nb * BB + b) * 1024 + o] = m;
    }
}

__global__ __launch_bounds__(256) void reduce32_kernel(const float* __restrict__ partial,
                                                       float* __restrict__ out) {
    int i = blockIdx.x * 256 + threadIdx.x;
    if (i >= BB * 1024) return;
    int b = i >> 10, o = i & 1023;
    float m = -__builtin_inff();
    #pragma unroll
    for (int nb = 0; nb < 32; ++nb)
        m = fmaxf(m, partial[(size_t)(nb * BB + b) * 1024 + o]);
    out[i] = m;
}

extern "C" void kernel_launch(void* const* d_in, const int* in_sizes, int n_in,
                              void* d_out, int out_size, void* d_ws, size_t ws_size,
                              hipStream_t stream) {
    const float* x  = (const float*)d_in[0];
    const float* W1 = (const float*)d_in[1];
    const float* g1 = (const float*)d_in[2];
    const float* b1 = (const float*)d_in[3];
    const float* W2 = (const float*)d_in[4];
    const float* g2 = (const float*)d_in[5];
    const float* b2 = (const float*)d_in[6];
    const float* W3 = (const float*)d_in[7];
    const float* g3 = (const float*)d_in[8];
    const float* b3 = (const float*)d_in[9];
    const float* W4 = (const float*)d_in[10];
    const float* g4 = (const float*)d_in[11];
    const float* b4 = (const float*)d_in[12];
    const float* W5 = (const float*)d_in[13];
    const float* g5 = (const float*)d_in[14];
    const float* b5 = (const float*)d_in[15];

    float* ws = (float*)d_ws;
    float*   sqv = ws;                          // 8192
    int*     idx = (int*)(ws + 8192);           // 163840 ints
    float*   x1  = ws + 8192 + 163840;          // 524288
    float*   x2  = x1 + 524288;                 // 524288
    float*   x3  = x2 + 524288;                 // 1048576
    float*   x4  = x3 + 1048576;                // 2097152
    float*   big = x4 + 2097152;                // p/tt region (and keys in new path)
    float*   p   = big;                         // 2097152
    float*   tt  = p + 2097152;                 // 2097152
    unsigned* keys = (unsigned*)big;            // 16777216 u32 (overlays p/tt)
    float*   W5T     = p;                       // reuse (dead after layer 4)
    float*   partial = tt;                      // reuse

    const size_t need_new = (size_t)(8192 + 163840 + 524288 + 524288 + 1048576
                                     + 2097152 + 16777216) * 4;
    const bool use_split = ws_size >= need_new;

    dim3 blk(256), kblk(512);

    if (use_split) {
        // ---- layer 1: C=3, O=64 ----
        sq_kernel<3><<<32, blk, 0, stream>>>(x, sqv);
        dist_kernel<3><<<BB * 32 * 32, blk, 0, stream>>>(x, sqv, keys);
        select_kernel<<<BB * NN / 4, blk, 0, stream>>>(keys, idx);
        pt_kernel<3, 16><<<BB * 4 * 8, blk, 0, stream>>>(x, W1, p, tt, 64);
        edge_kernel<<<BB * 64, blk, 0, stream>>>(p, tt, idx, g1, b1, x1, 64);

        // ---- layer 2: C=64, O=64 ----
        sq_kernel<64><<<32, blk, 0, stream>>>(x1, sqv);
        dist_kernel<64><<<BB * 32 * 32, blk, 0, stream>>>(x1, sqv, keys);
        select_kernel<<<BB * NN / 4, blk, 0, stream>>>(keys, idx);
        pt_kernel<64, 16><<<BB * 4 * 8, blk, 0, stream>>>(x1, W2, p, tt, 64);
        edge_kernel<<<BB * 64, blk, 0, stream>>>(p, tt, idx, g2, b2, x2, 64);

        // ---- layer 3: C=64, O=128 ----
        sq_kernel<64><<<32, blk, 0, stream>>>(x2, sqv);
        dist_kernel<64><<<BB * 32 * 32, blk, 0, stream>>>(x2, sqv, keys);
        select_kernel<<<BB * NN / 4, blk, 0, stream>>>(keys, idx);
        pt_kernel<64, 16><<<BB * 8 * 8, blk, 0, stream>>>(x2, W3, p, tt, 128);
        edge_kernel<<<BB * 128, blk, 0, stream>>>(p, tt, idx, g3, b3, x3, 128);

        // ---- layer 4: C=128, O=256 ----
        sq_kernel<128><<<32, blk, 0, stream>>>(x3, sqv);
        dist_kernel<128><<<BB * 32 * 32, blk, 0, stream>>>(x3, sqv, keys);
        select_kernel<<<BB * NN / 4, blk, 0, stream>>>(keys, idx);
        pt_kernel<128, 16><<<BB * 16 * 8, blk, 0, stream>>>(x3, W4, p, tt, 256);
        edge_kernel<<<BB * 256, blk, 0, stream>>>(p, tt, idx, g4, b4, x4, 256);
    } else {
        // ---- fallback: R10 fused path ----
        knn_kernel<3><<<BB * (NN / 8), kblk, 0, stream>>>(x, idx);
        pt_kernel<3, 16><<<BB * 4 * 8, blk, 0, stream>>>(x, W1, p, tt, 64);
        edge_kernel<<<BB * 64, blk, 0, stream>>>(p, tt, idx, g1, b1, x1, 64);

        knn_kernel<64><<<BB * (NN / 8), kblk, 0, stream>>>(x1, idx);
        pt_kernel<64, 16><<<BB * 4 * 8, blk, 0, stream>>>(x1, W2, p, tt, 64);
        edge_kernel<<<BB * 64, blk, 0, stream>>>(p, tt, idx, g2, b2, x2, 64);

        knn_kernel<64><<<BB * (NN / 8), kblk, 0, stream>>>(x2, idx);
        pt_kernel<64, 16><<<BB * 8 * 8, blk, 0, stream>>>(x2, W3, p, tt, 128);
        edge_kernel<<<BB * 128, blk, 0, stream>>>(p, tt, idx, g3, b3, x3, 128);

        knn_kernel<128><<<BB * (NN / 8), kblk, 0, stream>>>(x3, idx);
        pt_kernel<128, 16><<<BB * 16 * 8, blk, 0, stream>>>(x3, W4, p, tt, 256);
        edge_kernel<<<BB * 256, blk, 0, stream>>>(p, tt, idx, g4, b4, x4, 256);
    }

    // ---- layer 5: C=256, O=1024, fused max over n ----
    transpose_kernel<<<dim3(8, 32), dim3(32, 8), 0, stream>>>(W5, W5T);
    final_kernel<<<BB * 16 * 32, blk, 0, stream>>>(x4, W5T, g5, b5, partial);
    reduce32_kernel<<<16, blk, 0, stream>>>(partial, (float*)d_out);
}

// Round 12
// 515.114 us; speedup vs baseline: 1.1687x; 1.1687x over previous
//
#include <hip/hip_runtime.h>
#include <math.h>

#define BB 4
#define NN 2048
#define KK 20
#define INFPK 0xFFFFFFFFFFFFFFFFull

static __device__ __forceinline__ float lrelu(float z) {
    return z >= 0.f ? z : 0.2f * z;
}

// 64-bit full-wave min via paired 32-bit DPP (row_shr 1,2,4,8 + row_bcast 15,31),
// broadcast via readlane 63. Validated on this HW in R7-R11 (passed).
template<int CTRL>
static __device__ __forceinline__ unsigned long long dpp_min64_step(unsigned long long v) {
    unsigned lo = (unsigned)__builtin_amdgcn_update_dpp(
        (int)0xFFFFFFFFu, (int)(unsigned)v, CTRL, 0xF, 0xF, false);
    unsigned hi = (unsigned)__builtin_amdgcn_update_dpp(
        (int)0xFFFFFFFFu, (int)(unsigned)(v >> 32), CTRL, 0xF, 0xF, false);
    unsigned long long t = ((unsigned long long)hi << 32) | lo;
    return t < v ? t : v;
}
static __device__ __forceinline__ unsigned long long wave_min64_bcast(unsigned long long v) {
    v = dpp_min64_step<0x111>(v);
    v = dpp_min64_step<0x112>(v);
    v = dpp_min64_step<0x114>(v);
    v = dpp_min64_step<0x118>(v);
    v = dpp_min64_step<0x142>(v);
    v = dpp_min64_step<0x143>(v);
    unsigned lo = (unsigned)__builtin_amdgcn_readlane((int)(unsigned)v, 63);
    unsigned hi = (unsigned)__builtin_amdgcn_readlane((int)(unsigned)(v >> 32), 63);
    return ((unsigned long long)hi << 32) | lo;
}

// ---------------- fused knn (R10 structure, proven @514us total) ------------
// Block = 512 threads (8 waves) = (b, 8 queries); wave owns ONE query.
// sq fused (identical fmaf chains); distances bit-identical to all passing
// rounds; per-lane sorted top-4 u64 queue + DPP-min selection (R8-R10).
template<int C>
__global__ __launch_bounds__(512) void knn_kernel(const float* __restrict__ x,
                                                  int* __restrict__ idx) {
    const int QT = 8;
    __shared__ unsigned dl[QT][NN];
    __shared__ float xq[QT][C];
    __shared__ float sqq[QT];
    int blk = blockIdx.x;
    int b = blk / (NN / QT);
    int q0 = (blk - b * (NN / QT)) * QT;
    int t = threadIdx.x;
    int lane = t & 63, wid = t >> 6;

    const float* xb = x + (size_t)b * C * NN;
    for (int e = t; e < QT * C; e += 512) {
        int q = e / C, c = e - q * C;
        xq[q][c] = xb[(size_t)c * NN + q0 + q];
    }
    __syncthreads();
    if (t < QT) {
        float s = 0.f;
        #pragma unroll 4
        for (int c = 0; c < C; ++c) s = fmaf(xq[t][c], xq[t][c], s);
        sqq[t] = s;
    }
    __syncthreads();

    float acc[QT][4];
    #pragma unroll
    for (int q = 0; q < QT; ++q)
        #pragma unroll
        for (int u = 0; u < 4; ++u) acc[q][u] = 0.f;
    float sqa0 = 0.f, sqa1 = 0.f, sqa2 = 0.f, sqa3 = 0.f;

    for (int c = 0; c < C; ++c) {
        float4 xjv = *(const float4*)&xb[(size_t)c * NN + 4 * t];
        #pragma unroll
        for (int q = 0; q < QT; ++q) {
            float xqc = xq[q][c];
            acc[q][0] = fmaf(xqc, xjv.x, acc[q][0]);
            acc[q][1] = fmaf(xqc, xjv.y, acc[q][1]);
            acc[q][2] = fmaf(xqc, xjv.z, acc[q][2]);
            acc[q][3] = fmaf(xqc, xjv.w, acc[q][3]);
        }
        sqa0 = fmaf(xjv.x, xjv.x, sqa0);
        sqa1 = fmaf(xjv.y, xjv.y, sqa1);
        sqa2 = fmaf(xjv.z, xjv.z, sqa2);
        sqa3 = fmaf(xjv.w, xjv.w, sqa3);
    }
    float sqju[4] = {sqa0, sqa1, sqa2, sqa3};

    int wbase = ((t >> 3) << 5) | (((t ^ (t >> 3)) & 7) << 2);
    #pragma unroll
    for (int q = 0; q < QT; ++q) {
        float sqi = sqq[q];
        uint4 kv;
        unsigned ks[4];
        #pragma unroll
        for (int u = 0; u < 4; ++u) {
            float d = sqi + sqju[u] - 2.f * acc[q][u];
            unsigned v = __float_as_uint(d);
            ks[u] = v ^ ((unsigned)((int)v >> 31) | 0x80000000u);
        }
        kv.x = ks[0]; kv.y = ks[1]; kv.z = ks[2]; kv.w = ks[3];
        *(uint4*)&dl[q][wbase] = kv;
    }
    __syncthreads();

    unsigned* dq = &dl[wid][0];
    int r7 = lane & 7;
    int lanebase = lane << 5;
    unsigned long long h0 = INFPK, h1 = INFPK, h2 = INFPK, h3 = INFPK;

#define PK_INS(KEY, LO) {                                                     \
        unsigned long long v =                                                \
            ((unsigned long long)(KEY) << 12) | (unsigned)(lanebase + (LO));  \
        if (v < h3) {                                                         \
            unsigned long long nh3 = h2 > v ? h2 : v;                         \
            unsigned long long t2  = h2 < v ? h2 : v;                         \
            unsigned long long nh2 = h1 > t2 ? h1 : t2;                       \
            unsigned long long t1  = h1 < v ? h1 : v;                         \
            unsigned long long nh1 = h0 > t1 ? h0 : t1;                       \
            unsigned long long nh0 = h0 < v ? h0 : v;                         \
            h0 = nh0; h1 = nh1; h2 = nh2; h3 = nh3;                           \
        } }
#define PK_INS_THR(KEY, LO) {                                                 \
        unsigned long long v =                                                \
            ((unsigned long long)(KEY) << 12) | (unsigned)(lanebase + (LO));  \
        if (v > thr && v < h3) {                                              \
            unsigned long long nh3 = h2 > v ? h2 : v;                         \
            unsigned long long t2  = h2 < v ? h2 : v;                         \
            unsigned long long nh2 = h1 > t2 ? h1 : t2;                       \
            unsigned long long t1  = h1 < v ? h1 : v;                         \
            unsigned long long nh1 = h0 > t1 ? h0 : t1;                       \
            unsigned long long nh0 = h0 < v ? h0 : v;                         \
            h0 = nh0; h1 = nh1; h2 = nh2; h3 = nh3;                           \
        } }
#define CHUNK_RD(c) uint4 V##c = *(const uint4*)(dq + lanebase + (((c) ^ r7) << 2));
#define CHUNK_INS(c)     { PK_INS(V##c.x, 4*(c)+0) PK_INS(V##c.y, 4*(c)+1)        \
                           PK_INS(V##c.z, 4*(c)+2) PK_INS(V##c.w, 4*(c)+3) }
#define CHUNK_INS_THR(c) { PK_INS_THR(V##c.x, 4*(c)+0) PK_INS_THR(V##c.y, 4*(c)+1) \
                           PK_INS_THR(V##c.z, 4*(c)+2) PK_INS_THR(V##c.w, 4*(c)+3) }

    {
        CHUNK_RD(0) CHUNK_RD(1) CHUNK_RD(2) CHUNK_RD(3)
        CHUNK_RD(4) CHUNK_RD(5) CHUNK_RD(6) CHUNK_RD(7)
        CHUNK_INS(0) CHUNK_INS(1) CHUNK_INS(2) CHUNK_INS(3)
        CHUNK_INS(4) CHUNK_INS(5) CHUNK_INS(6) CHUNK_INS(7)
    }

    int* orow = idx + (size_t)(b * NN + q0 + wid) * KK;
    unsigned long long thr = 0;
    int popped = 0;
    #pragma unroll 1
    for (int rr = 0; rr < KK; ++rr) {
        unsigned long long g = wave_min64_bcast(h0);
        if (lane == 0) orow[rr] = (int)(g & 0xFFFu);
        if (h0 == g) {
            thr = g;
            ++popped;
            h0 = h1; h1 = h2; h2 = h3; h3 = INFPK;
            if (h0 == INFPK && popped < 32) {
                CHUNK_RD(0) CHUNK_RD(1) CHUNK_RD(2) CHUNK_RD(3)
                CHUNK_RD(4) CHUNK_RD(5) CHUNK_RD(6) CHUNK_RD(7)
                CHUNK_INS_THR(0) CHUNK_INS_THR(1) CHUNK_INS_THR(2) CHUNK_INS_THR(3)
                CHUNK_INS_THR(4) CHUNK_INS_THR(5) CHUNK_INS_THR(6) CHUNK_INS_THR(7)
            }
        }
    }
#undef PK_INS
#undef PK_INS_THR
#undef CHUNK_RD
#undef CHUNK_INS
#undef CHUNK_INS_THR
}

// ---------------- p/t: p = Wn·x, t = (Wc-Wn)·x ----------------
template<int C, int OT>
__global__ __launch_bounds__(256) void pt_kernel(const float* __restrict__ x,
                                                 const float* __restrict__ W,
                                                 float* __restrict__ p,
                                                 float* __restrict__ tt,
                                                 int O) {
    const int NB = NN / 256;
    int blk = blockIdx.x;
    int nb = blk % NB;
    int rest = blk / NB;
    int nob = O / OT;
    int ob = rest % nob;
    int b = rest / nob;
    int t = threadIdx.x;
    int n = nb * 256 + t;
    __shared__ float wn[OT][C], wd[OT][C];
    for (int e = t; e < OT * C; e += 256) {
        int o = e / C, c = e - o * C;
        float a = W[(size_t)(ob * OT + o) * (2 * C) + c];
        float b2 = W[(size_t)(ob * OT + o) * (2 * C) + C + c];
        wn[o][c] = a;
        wd[o][c] = b2 - a;
    }
    __syncthreads();
    float ap[OT], at[OT];
    #pragma unroll
    for (int o = 0; o < OT; ++o) { ap[o] = 0.f; at[o] = 0.f; }
    const float* xb = x + (size_t)b * C * NN + n;
    for (int c = 0; c < C; ++c) {
        float xv = xb[(size_t)c * NN];
        #pragma unroll
        for (int o = 0; o < OT; ++o) {
            ap[o] = fmaf(wn[o][c], xv, ap[o]);
            at[o] = fmaf(wd[o][c], xv, at[o]);
        }
    }
    size_t base = ((size_t)b * O + ob * OT) * NN + n;
    #pragma unroll
    for (int o = 0; o < OT; ++o) {
        p[base + (size_t)o * NN] = ap[o];
        tt[base + (size_t)o * NN] = at[o];
    }
}

// ---------------- edge max ----------------
__global__ __launch_bounds__(256) void edge_kernel(const float* __restrict__ p,
                                                   const float* __restrict__ tt,
                                                   const int* __restrict__ idx,
                                                   const float* __restrict__ g,
                                                   const float* __restrict__ be,
                                                   float* __restrict__ out, int O) {
    int b = blockIdx.x / O, o = blockIdx.x - b * O;
    __shared__ float pl[NN];
    const float* pr = p + ((size_t)b * O + o) * NN;
    for (int e = threadIdx.x * 4; e < NN; e += 1024)
        *(float4*)&pl[e] = *(const float4*)&pr[e];
    __syncthreads();
    float scale = g[o] / sqrtf(1.f + 1e-5f);
    float beta = be[o];
    const float* tr = tt + ((size_t)b * O + o) * NN;
    float* orow = out + ((size_t)b * O + o) * NN;
    for (int i = threadIdx.x; i < NN; i += 256) {
        float ti = tr[i];
        const int4* ir4 = (const int4*)(idx + (size_t)(b * NN + i) * KK);
        int4 w0 = ir4[0], w1 = ir4[1], w2 = ir4[2], w3 = ir4[3], w4 = ir4[4];
        float m = -__builtin_inff();
        int js[20] = {w0.x, w0.y, w0.z, w0.w, w1.x, w1.y, w1.z, w1.w,
                      w2.x, w2.y, w2.z, w2.w, w3.x, w3.y, w3.z, w3.w,
                      w4.x, w4.y, w4.z, w4.w};
        #pragma unroll
        for (int k = 0; k < KK; ++k) {
            float y = pl[js[k]] + ti;
            m = fmaxf(m, lrelu(fmaf(scale, y, beta)));
        }
        orow[i] = m;
    }
}

// ---------------- transpose W5 [1024][256] -> W5T [256][1024] ----------------
__global__ __launch_bounds__(256) void transpose_kernel(const float* __restrict__ W,
                                                        float* __restrict__ WT) {
    __shared__ float tile[32][33];
    int c0 = blockIdx.x * 32, o0 = blockIdx.y * 32;
    int tx = threadIdx.x, ty = threadIdx.y;
    #pragma unroll
    for (int i = 0; i < 32; i += 8)
        tile[ty + i][tx] = W[(size_t)(o0 + ty + i) * 256 + c0 + tx];
    __syncthreads();
    #pragma unroll
    for (int i = 0; i < 32; i += 8)
        WT[(size_t)(c0 + ty + i) * 1024 + o0 + tx] = tile[tx][ty + i];
}

// ---------------- final: 128x128 block tile, 8x8/thread, fused lrelu+max ----
// Thread tile split as two quads: n in {tn*4, 64+tn*4}, o in {to*4, 64+to*4}
// -> LDS reads are 2-way aliased (free, m136) or broadcast. DS-pipe per FMA
// halved vs the 64x64 version (2048 blocks -> 512; L2 operand traffic halved).
// Max over n is order-invariant so the n-split is safe; o handled as 2 quads.
__global__ __launch_bounds__(256) void final_kernel(const float* __restrict__ x4,
                                                    const float* __restrict__ W5T,
                                                    const float* __restrict__ g,
                                                    const float* __restrict__ be,
                                                    float* __restrict__ partial) {
    const int CC = 256;
    __shared__ float xs[32][128];   // [c][n] 16 KB
    __shared__ float ws[32][128];   // [c][o] 16 KB
    int blk = blockIdx.x;
    int nb = blk & 15;
    int ob = (blk >> 4) & 7;
    int b  = blk >> 7;
    int t = threadIdx.x;
    int tn = t & 15, to = t >> 4;

    float acc[8][8];   // [o(2 quads)][n(2 quads)]
    #pragma unroll
    for (int i = 0; i < 8; ++i)
        #pragma unroll
        for (int j = 0; j < 8; ++j) acc[i][j] = 0.f;

    for (int c0 = 0; c0 < CC; c0 += 32) {
        __syncthreads();
        #pragma unroll
        for (int e = t * 4; e < 32 * 128; e += 1024) {
            int c = e >> 7, n = e & 127;
            *(float4*)&xs[c][n] =
                *(const float4*)&x4[((size_t)b * CC + c0 + c) * NN + nb * 128 + n];
        }
        #pragma unroll
        for (int e = t * 4; e < 32 * 128; e += 1024) {
            int c = e >> 7, o = e & 127;
            *(float4*)&ws[c][o] =
                *(const float4*)&W5T[(size_t)(c0 + c) * 1024 + ob * 128 + o];
        }
        __syncthreads();
        for (int c = 0; c < 32; ++c) {
            float4 xv0 = *(float4*)&xs[c][tn * 4];
            float4 xv1 = *(float4*)&xs[c][64 + tn * 4];
            float4 wv0 = *(float4*)&ws[c][to * 4];
            float4 wv1 = *(float4*)&ws[c][64 + to * 4];
            float xn[8] = {xv0.x, xv0.y, xv0.z, xv0.w, xv1.x, xv1.y, xv1.z, xv1.w};
            float wo[8] = {wv0.x, wv0.y, wv0.z, wv0.w, wv1.x, wv1.y, wv1.z, wv1.w};
            #pragma unroll
            for (int i = 0; i < 8; ++i)
                #pragma unroll
                for (int j = 0; j < 8; ++j)
                    acc[i][j] = fmaf(wo[i], xn[j], acc[i][j]);
        }
    }

    float rs = 1.f / sqrtf(1.f + 1e-5f);
    #pragma unroll
    for (int i = 0; i < 8; ++i) {
        int o = ob * 128 + ((i < 4) ? (to * 4 + i) : (64 + to * 4 + i - 4));
        float scale = g[o] * rs, beta = be[o];
        float m = -__builtin_inff();
        #pragma unroll
        for (int j = 0; j < 8; ++j)
            m = fmaxf(m, lrelu(fmaf(scale, acc[i][j], beta)));
        // reduce over the 16 tn-lanes sharing this to (low 4 lane bits)
        #pragma unroll
        for (int off = 8; off >= 1; off >>= 1)
            m = fmaxf(m, __shfl_xor(m, off));
        if (tn == 0)
            partial[(size_t)(nb * BB + b) * 1024 + o] = m;
    }
}

__global__ __launch_bounds__(256) void reduce16_kernel(const float* __restrict__ partial,
                                                       float* __restrict__ out) {
    int i = blockIdx.x * 256 + threadIdx.x;
    if (i >= BB * 1024) return;
    int b = i >> 10, o = i & 1023;
    float m = -__builtin_inff();
    #pragma unroll
    for (int nb = 0; nb < 16; ++nb)
        m = fmaxf(m, partial[(size_t)(nb * BB + b) * 1024 + o]);
    out[i] = m;
}

extern "C" void kernel_launch(void* const* d_in, const int* in_sizes, int n_in,
                              void* d_out, int out_size, void* d_ws, size_t ws_size,
                              hipStream_t stream) {
    const float* x  = (const float*)d_in[0];
    const float* W1 = (const float*)d_in[1];
    const float* g1 = (const float*)d_in[2];
    const float* b1 = (const float*)d_in[3];
    const float* W2 = (const float*)d_in[4];
    const float* g2 = (const float*)d_in[5];
    const float* b2 = (const float*)d_in[6];
    const float* W3 = (const float*)d_in[7];
    const float* g3 = (const float*)d_in[8];
    const float* b3 = (const float*)d_in[9];
    const float* W4 = (const float*)d_in[10];
    const float* g4 = (const float*)d_in[11];
    const float* b4 = (const float*)d_in[12];
    const float* W5 = (const float*)d_in[13];
    const float* g5 = (const float*)d_in[14];
    const float* b5 = (const float*)d_in[15];

    float* ws = (float*)d_ws;
    int*   idx     = (int*)(ws + 8192);        // 163840 ints (offset kept stable)
    float* x1      = ws + 8192 + 163840;       // 524288
    float* x2      = x1 + 524288;              // 524288
    float* x3      = x2 + 524288;              // 1048576
    float* x4      = x3 + 1048576;             // 2097152
    float* p       = x4 + 2097152;             // 2097152
    float* tt      = p + 2097152;              // 2097152
    float* W5T     = p;                        // reuse (dead after layer 4)
    float* partial = tt;                       // reuse

    dim3 blk(256), kblk(512);

    // ---- layer 1: C=3, O=64 ----
    knn_kernel<3><<<BB * (NN / 8), kblk, 0, stream>>>(x, idx);
    pt_kernel<3, 16><<<BB * 4 * 8, blk, 0, stream>>>(x, W1, p, tt, 64);
    edge_kernel<<<BB * 64, blk, 0, stream>>>(p, tt, idx, g1, b1, x1, 64);

    // ---- layer 2: C=64, O=64 ----
    knn_kernel<64><<<BB * (NN / 8), kblk, 0, stream>>>(x1, idx);
    pt_kernel<64, 16><<<BB * 4 * 8, blk, 0, stream>>>(x1, W2, p, tt, 64);
    edge_kernel<<<BB * 64, blk, 0, stream>>>(p, tt, idx, g2, b2, x2, 64);

    // ---- layer 3: C=64, O=128 ----
    knn_kernel<64><<<BB * (NN / 8), kblk, 0, stream>>>(x2, idx);
    pt_kernel<64, 16><<<BB * 8 * 8, blk, 0, stream>>>(x2, W3, p, tt, 128);
    edge_kernel<<<BB * 128, blk, 0, stream>>>(p, tt, idx, g3, b3, x3, 128);

    // ---- layer 4: C=128, O=256 ----
    knn_kernel<128><<<BB * (NN / 8), kblk, 0, stream>>>(x3, idx);
    pt_kernel<128, 16><<<BB * 16 * 8, blk, 0, stream>>>(x3, W4, p, tt, 256);
    edge_kernel<<<BB * 256, blk, 0, stream>>>(p, tt, idx, g4, b4, x4, 256);

    // ---- layer 5: C=256, O=1024, fused max over n ----
    transpose_kernel<<<dim3(8, 32), dim3(32, 8), 0, stream>>>(W5, W5T);
    final_kernel<<<BB * 8 * 16, blk, 0, stream>>>(x4, W5T, g5, b5, partial);
    reduce16_kernel<<<16, blk, 0, stream>>>(partial, (float*)d_out);
}